// Round 13
// baseline (550.800 us; speedup 1.0000x reference)
//
#include <hip/hip_runtime.h>

#define E_DIM  256
#define N_E    16384
#define N_ROWS 8192
#define HW     1024
#define NPART  128          // n-tiles of 128 cols

typedef _Float16 f16x8 __attribute__((ext_vector_type(8)));
typedef float    f32x4 __attribute__((ext_vector_type(4)));

#define ESCALE   1048576.0f          // 2^20 (exact)
#define UNSCALE  1.9073486328125e-6f // 2^-19: acc*2^-19 == 2*dot

// async 16B global->LDS copy: HW writes lds_base + lane*16 (wave-uniform base)
__device__ __forceinline__ void gld_lds16(_Float16* lds, const _Float16* g) {
  __builtin_amdgcn_global_load_lds(
      (__attribute__((address_space(1))) void*)(g),
      (__attribute__((address_space(3))) void*)(lds), 16, 0, 0);
}

// ---------- fused prep (verbatim R11, passed) ----------
#define ZB_Z    256
#define EB_E    512
__global__ __launch_bounds__(256) void k_prep(const float* __restrict__ z,
                                              const float* __restrict__ E,
                                              _Float16* __restrict__ Ah,
                                              _Float16* __restrict__ Al,
                                              _Float16* __restrict__ Bh,
                                              _Float16* __restrict__ Bl,
                                              float* __restrict__ eNorm,
                                              float* __restrict__ zNorm,
                                              float* __restrict__ out_loss) {
#pragma clang fp contract(off)
  const int bi = blockIdx.x, t = threadIdx.x;

  if (bi < ZB_Z) {
    // ---- z section: 32-row tile ----
    __shared__ float sLZ[256][32];   // 32 KB z tile [channel][row]
    __shared__ float sN2[16][32];    // chain partials [c16][row]
    const int n0 = bi * 32;
    const int b = n0 >> 10, hw0 = n0 & 1023;

    {
      const int nl = t & 31, cs = t >> 5;
      const float* zb = z + (size_t)b * E_DIM * HW + hw0 + nl;
#pragma unroll 4
      for (int it = 0; it < 32; ++it) {
        int c = it * 8 + cs;
        sLZ[c][nl] = zb[(size_t)c * HW];
      }
    }
    __syncthreads();

    // phase L: limbs. thread = (row nl, segment seg = kc)
    {
      const int nl = t & 31, seg = t >> 5;
      const int n = n0 + nl;
      const int perm = (n >> 1) & 3;
#pragma unroll
      for (int u = 0; u < 4; ++u) {
        const int c0 = seg * 32 + u * 8;
        f16x8 hh, ll;
#pragma unroll
        for (int j = 0; j < 8; ++j) {
          float v = sLZ[c0 + j][nl];
          _Float16 hi = (_Float16)v;
          hh[j] = hi;
          ll[j] = (_Float16)(v - (float)hi);
        }
        size_t dst = (size_t)seg * (N_ROWS * 32) + (size_t)n * 32 + (size_t)(u ^ perm) * 8;
        *(f16x8*)&Ah[dst] = hh;
        *(f16x8*)&Al[dst] = ll;
      }
    }

    // phase N: numpy-exact chains
#pragma unroll
    for (int it = 0; it < 2; ++it) {
      int task = it * 256 + t;
      int nl = task & 31, c16 = task >> 5;
      int h = c16 >> 3, j = c16 & 7;
      float r = 0.f;
#pragma unroll
      for (int i = 0; i < 16; ++i) {
        float v = sLZ[h * 128 + i * 8 + j][nl];
        r = r + v * v;
      }
      sN2[c16][nl] = r;
    }
    __syncthreads();
    if (t < 32) {
      float q[16];
#pragma unroll
      for (int c16 = 0; c16 < 16; ++c16) q[c16] = sN2[c16][t];
      float h0 = ((q[0] + q[1]) + (q[2] + q[3])) + ((q[4] + q[5]) + (q[6] + q[7]));
      float h1 = ((q[8] + q[9]) + (q[10] + q[11])) + ((q[12] + q[13]) + (q[14] + q[15]));
      zNorm[n0 + t] = h0 + h1;
    }
  } else {
    // ---- E section ----
    __shared__ float sNP[8][32];
    const int be = bi - ZB_Z;
    if (be == 0 && t == 0) out_loss[0] = 0.f;
    const int kc = t >> 5, rl = t & 31;
    const int k = be * 32 + rl;
    const int perm = (k >> 1) & 3;
    const float* src = E + (size_t)k * E_DIM + kc * 32;

    float4 v4[8];
#pragma unroll
    for (int u2 = 0; u2 < 8; ++u2) v4[u2] = ((const float4*)src)[u2];

    float nsum = 0.f;
    size_t base = (size_t)kc * (N_E * 32) + (size_t)k * 32;
#pragma unroll
    for (int u = 0; u < 4; ++u) {
      float v[8] = {v4[u * 2].x, v4[u * 2].y, v4[u * 2].z, v4[u * 2].w,
                    v4[u * 2 + 1].x, v4[u * 2 + 1].y, v4[u * 2 + 1].z, v4[u * 2 + 1].w};
      f16x8 hh, ll;
#pragma unroll
      for (int j = 0; j < 8; ++j) {
        nsum = nsum + v[j] * v[j];
        float s = v[j] * ESCALE;
        _Float16 hi = (_Float16)s;
        hh[j] = hi;
        ll[j] = (_Float16)(s - (float)hi);
      }
      *(f16x8*)&Bh[base + (size_t)(u ^ perm) * 8] = hh;
      *(f16x8*)&Bl[base + (size_t)(u ^ perm) * 8] = ll;
    }
    sNP[kc][rl] = nsum;
    __syncthreads();
    if (t < 32) {
      float s = 0.f;
#pragma unroll
      for (int kc2 = 0; kc2 < 8; ++kc2) s += sNP[kc2][t];
      eNorm[be * 32 + t] = s;
    }
  }
}

// ---------- main: 3-pass fp16-limb MFMA GEMM, block 128x128, wave 64x64 ----------
// R13: launch_bounds min-waves 4 -> 5 (LDS allows 5 blocks/CU; VGPR cap 102 >= 64).
// R12 result: 3->4 gave occupancy 32.7->42.8%, MfmaUtil 37.9->42.6%, 245.6->226.4 us.
__global__ __launch_bounds__(256, 5) void k_scores_mfma(
    const _Float16* __restrict__ Ah, const _Float16* __restrict__ Al,
    const _Float16* __restrict__ Bh, const _Float16* __restrict__ Bl,
    const float* __restrict__ eNorm, const float* __restrict__ zNorm,
    float* __restrict__ pVal, int* __restrict__ pIdx) {
#pragma clang fp contract(off)
  __shared__ alignas(16) _Float16 As[2][128][32];  // 16 KB: limb, row, swizzled 32 f16
  __shared__ alignas(16) _Float16 Bs[2][128][32];  // 16 KB

  const int mt = blockIdx.x, nt = blockIdx.y;
  const int m0 = mt * 128, n0 = nt * 128;

  const int t = threadIdx.x;
  const int lane = t & 63, w = t >> 6;
  const int tx = lane & 15, quad = lane >> 4;
  const int wm = (w >> 1) * 64, wn = (w & 1) * 64;
  const int swz = (quad ^ ((tx >> 1) & 3)) * 8;    // physical f16 offset of logical block

  const _Float16* gseg;
  size_t plane;
  _Float16* lseg;
  if (w == 0)      { gseg = Ah + (size_t)m0 * 32; plane = (size_t)N_ROWS * 32; lseg = &As[0][0][0]; }
  else if (w == 1) { gseg = Al + (size_t)m0 * 32; plane = (size_t)N_ROWS * 32; lseg = &As[1][0][0]; }
  else if (w == 2) { gseg = Bh + (size_t)n0 * 32; plane = (size_t)N_E * 32;    lseg = &Bs[0][0][0]; }
  else             { gseg = Bl + (size_t)n0 * 32; plane = (size_t)N_E * 32;    lseg = &Bs[1][0][0]; }

  f32x4 acc[4][4];
#pragma unroll
  for (int i = 0; i < 4; ++i)
#pragma unroll
    for (int j = 0; j < 4; ++j) acc[i][j] = (f32x4){0.f, 0.f, 0.f, 0.f};

  for (int kc = 0; kc < 8; ++kc) {
    __syncthreads();                       // previous iteration's frag reads done
    const _Float16* g = gseg + (size_t)kc * plane + lane * 8;
#pragma unroll
    for (int c = 0; c < 8; ++c)
      gld_lds16(lseg + c * 512, g + c * 512);   // 8 x 1KB async copies per wave
    __syncthreads();                       // vmcnt(0) drained before barrier -> data visible

    f16x8 bh[4], bl[4];
#pragma unroll
    for (int j = 0; j < 4; ++j) {
      bh[j] = *(const f16x8*)&Bs[0][wn + j * 16 + tx][swz];
      bl[j] = *(const f16x8*)&Bs[1][wn + j * 16 + tx][swz];
    }
#pragma unroll
    for (int i = 0; i < 4; ++i) {
      f16x8 ah = *(const f16x8*)&As[0][wm + i * 16 + tx][swz];
      f16x8 al = *(const f16x8*)&As[1][wm + i * 16 + tx][swz];
#pragma unroll
      for (int j = 0; j < 4; ++j) {
        acc[i][j] = __builtin_amdgcn_mfma_f32_16x16x32_f16(ah, bh[j], acc[i][j], 0, 0, 0);
        acc[i][j] = __builtin_amdgcn_mfma_f32_16x16x32_f16(ah, bl[j], acc[i][j], 0, 0, 0);
        acc[i][j] = __builtin_amdgcn_mfma_f32_16x16x32_f16(al, bh[j], acc[i][j], 0, 0, 0);
      }
    }
  }

  // ---- epilogue: score + argmin (first-index tie-break) ----
  __syncthreads();
  float* sF  = (float*)&As[0][0][0];
  float* zNl = sF;                 // [128]
  float* eNl = sF + 128;           // [128]
  float* sV  = sF + 256;           // [2][128]
  int*   sI  = (int*)(sF + 512);   // [2][128]
  if (t < 128) zNl[t] = zNorm[m0 + t];
  else         eNl[t - 128] = eNorm[n0 + t - 128];
  __syncthreads();

#pragma unroll
  for (int i = 0; i < 4; ++i) {
#pragma unroll
    for (int r = 0; r < 4; ++r) {
      const int rloc = wm + i * 16 + quad * 4 + r;
      const float zn = zNl[rloc];
      float bv = 3.4e38f;
      int bc = 0x7fffffff;
#pragma unroll
      for (int j = 0; j < 4; ++j) {
        const int col = wn + j * 16 + tx;
        float s = (zn + eNl[col]) - acc[i][j][r] * UNSCALE;
        if (s < bv) { bv = s; bc = n0 + col; }   // j ascending: strict < keeps lowest col
      }
#pragma unroll
      for (int off = 1; off < 16; off <<= 1) {
        float ov = __shfl_xor(bv, off, 64);
        int oc = __shfl_xor(bc, off, 64);
        if (ov < bv || (ov == bv && oc < bc)) { bv = ov; bc = oc; }
      }
      if (tx == 0) { sV[(w & 1) * 128 + rloc] = bv; sI[(w & 1) * 128 + rloc] = bc; }
    }
  }
  __syncthreads();
  if (t < 128) {
    float v0 = sV[t], v1 = sV[128 + t];
    int i0 = sI[t], i1 = sI[128 + t];
    int take1 = (v1 < v0) || (v1 == v0 && i1 < i0);
    pVal[(size_t)nt * N_ROWS + m0 + t] = take1 ? v1 : v0;
    pIdx[(size_t)nt * N_ROWS + m0 + t] = take1 ? i1 : i0;
  }
}

// ---------- fused post (verbatim R11, passed) ----------
__global__ __launch_bounds__(256) void k_post(const float* __restrict__ pVal,
                                              const int* __restrict__ pIdx,
                                              const float* __restrict__ z,
                                              const float* __restrict__ E,
                                              float* __restrict__ out,
                                              float* __restrict__ out_loss,
                                              float* __restrict__ out_idx) {
  __shared__ float sV[8][32];
  __shared__ int   sI[8][32];
  __shared__ int   fI[32];
  const int t = threadIdx.x;
  const int r = t & 31, s = t >> 5;
  const int n0 = blockIdx.x * 32;
  const int n = n0 + r;

  float mv = 3.4e38f;
  int mi = 0x7fffffff;
#pragma unroll
  for (int i = 0; i < 16; ++i) {
    int s2 = s * 16 + i;
    float v = pVal[(size_t)s2 * N_ROWS + n];
    int id = pIdx[(size_t)s2 * N_ROWS + n];
    if (v < mv || (v == mv && id < mi)) { mv = v; mi = id; }
  }
  sV[s][r] = mv;
  sI[s][r] = mi;
  __syncthreads();
  if (t < 32) {
    float bv = sV[0][t];
    int bc = sI[0][t];
#pragma unroll
    for (int s3 = 1; s3 < 8; ++s3) {
      float v = sV[s3][t];
      int id = sI[s3][t];
      if (v < bv || (v == bv && id < bc)) { bv = v; bc = id; }
    }
    fI[t] = bc;
    out_idx[n0 + t] = (float)bc;
  }
  __syncthreads();

  const int idx = fI[r];
  const int b = n >> 10, hw = n & 1023;
  const float4* erow4 = (const float4*)(E + (size_t)idx * E_DIM + s * 32);
  const float* zrow = z + ((size_t)b * E_DIM + s * 32) * HW + hw;
  float* orow = out + ((size_t)b * E_DIM + s * 32) * HW + hw;
  float acc = 0.f;
#pragma unroll
  for (int c4 = 0; c4 < 8; ++c4) {
    float4 e4 = erow4[c4];
    float ev[4] = {e4.x, e4.y, e4.z, e4.w};
#pragma unroll
    for (int j2 = 0; j2 < 4; ++j2) {
      int c = c4 * 4 + j2;
      float zv = zrow[(size_t)c * HW];
      orow[(size_t)c * HW] = ev[j2];
      float d = ev[j2] - zv;
      acc = fmaf(d, d, acc);
    }
  }
  for (int off = 32; off > 0; off >>= 1) acc += __shfl_down(acc, off, 64);
  __shared__ float wsum[4];
  if ((t & 63) == 0) wsum[t >> 6] = acc;
  __syncthreads();
  if (t == 0)
    atomicAdd(out_loss, ((wsum[0] + wsum[1]) + (wsum[2] + wsum[3])) * (1.25f / 2097152.f));
}

extern "C" void kernel_launch(void* const* d_in, const int* in_sizes, int n_in,
                              void* d_out, int out_size, void* d_ws, size_t ws_size,
                              hipStream_t stream) {
  const float* z = (const float*)d_in[0];
  const float* E = (const float*)d_in[1];
  float* out = (float*)d_out;
  float* out_loss = out + 2097152;  // after z_q (8*256*32*32)
  float* out_idx = out + 2097153;

  // workspace (~32 MB): Ah|Al f16[8][8192][32], Bh|Bl f16[8][16384][32],
  //                     eNorm, zNorm, pVal[128][8192], pIdx[128][8192]
  _Float16* Ah = (_Float16*)d_ws;
  _Float16* Al = Ah + (size_t)N_ROWS * E_DIM;
  _Float16* Bh = Al + (size_t)N_ROWS * E_DIM;
  _Float16* Bl = Bh + (size_t)N_E * E_DIM;
  float* eNorm = (float*)(Bl + (size_t)N_E * E_DIM);
  float* zNorm = eNorm + N_E;
  float* pVal = zNorm + N_ROWS;
  int* pIdx = (int*)(pVal + (size_t)NPART * N_ROWS);

  k_prep<<<ZB_Z + EB_E, 256, 0, stream>>>(
      z, E, Ah, Al, Bh, Bl, eNorm, zNorm, out_loss);
  k_scores_mfma<<<dim3(N_ROWS / 128, N_E / 128), 256, 0, stream>>>(
      Ah, Al, Bh, Bl, eNorm, zNorm, pVal, pIdx);
  k_post<<<N_ROWS / 32, 256, 0, stream>>>(pVal, pIdx, z, E, out, out_loss, out_idx);
}

// Round 14
// 314.303 us; speedup vs baseline: 1.7524x; 1.7524x over previous
//
#include <hip/hip_runtime.h>

#define E_DIM  256
#define N_E    16384
#define N_ROWS 8192
#define HW     1024
#define NPART  128          // n-tiles of 128 cols

typedef _Float16 f16x8 __attribute__((ext_vector_type(8)));
typedef float    f32x4 __attribute__((ext_vector_type(4)));

#define ESCALE   1048576.0f          // 2^20 (exact)
#define UNSCALE  1.9073486328125e-6f // 2^-19: acc*2^-19 == 2*dot

// async 16B global->LDS copy: HW writes lds_base + lane*16 (wave-uniform base)
__device__ __forceinline__ void gld_lds16(_Float16* lds, const _Float16* g) {
  __builtin_amdgcn_global_load_lds(
      (__attribute__((address_space(1))) void*)(g),
      (__attribute__((address_space(3))) void*)(lds), 16, 0, 0);
}

// ---------- fused prep (verbatim R11/R12, passed) ----------
#define ZB_Z    256
#define EB_E    512
__global__ __launch_bounds__(256) void k_prep(const float* __restrict__ z,
                                              const float* __restrict__ E,
                                              _Float16* __restrict__ Ah,
                                              _Float16* __restrict__ Al,
                                              _Float16* __restrict__ Bh,
                                              _Float16* __restrict__ Bl,
                                              float* __restrict__ eNorm,
                                              float* __restrict__ zNorm,
                                              float* __restrict__ out_loss) {
#pragma clang fp contract(off)
  const int bi = blockIdx.x, t = threadIdx.x;

  if (bi < ZB_Z) {
    // ---- z section: 32-row tile ----
    __shared__ float sLZ[256][32];   // 32 KB z tile [channel][row]
    __shared__ float sN2[16][32];    // chain partials [c16][row]
    const int n0 = bi * 32;
    const int b = n0 >> 10, hw0 = n0 & 1023;

    {
      const int nl = t & 31, cs = t >> 5;
      const float* zb = z + (size_t)b * E_DIM * HW + hw0 + nl;
#pragma unroll 4
      for (int it = 0; it < 32; ++it) {
        int c = it * 8 + cs;
        sLZ[c][nl] = zb[(size_t)c * HW];
      }
    }
    __syncthreads();

    // phase L: limbs. thread = (row nl, segment seg = kc)
    {
      const int nl = t & 31, seg = t >> 5;
      const int n = n0 + nl;
      const int perm = (n >> 1) & 3;
#pragma unroll
      for (int u = 0; u < 4; ++u) {
        const int c0 = seg * 32 + u * 8;
        f16x8 hh, ll;
#pragma unroll
        for (int j = 0; j < 8; ++j) {
          float v = sLZ[c0 + j][nl];
          _Float16 hi = (_Float16)v;
          hh[j] = hi;
          ll[j] = (_Float16)(v - (float)hi);
        }
        size_t dst = (size_t)seg * (N_ROWS * 32) + (size_t)n * 32 + (size_t)(u ^ perm) * 8;
        *(f16x8*)&Ah[dst] = hh;
        *(f16x8*)&Al[dst] = ll;
      }
    }

    // phase N: numpy-exact chains
#pragma unroll
    for (int it = 0; it < 2; ++it) {
      int task = it * 256 + t;
      int nl = task & 31, c16 = task >> 5;
      int h = c16 >> 3, j = c16 & 7;
      float r = 0.f;
#pragma unroll
      for (int i = 0; i < 16; ++i) {
        float v = sLZ[h * 128 + i * 8 + j][nl];
        r = r + v * v;
      }
      sN2[c16][nl] = r;
    }
    __syncthreads();
    if (t < 32) {
      float q[16];
#pragma unroll
      for (int c16 = 0; c16 < 16; ++c16) q[c16] = sN2[c16][t];
      float h0 = ((q[0] + q[1]) + (q[2] + q[3])) + ((q[4] + q[5]) + (q[6] + q[7]));
      float h1 = ((q[8] + q[9]) + (q[10] + q[11])) + ((q[12] + q[13]) + (q[14] + q[15]));
      zNorm[n0 + t] = h0 + h1;
    }
  } else {
    // ---- E section ----
    __shared__ float sNP[8][32];
    const int be = bi - ZB_Z;
    if (be == 0 && t == 0) out_loss[0] = 0.f;
    const int kc = t >> 5, rl = t & 31;
    const int k = be * 32 + rl;
    const int perm = (k >> 1) & 3;
    const float* src = E + (size_t)k * E_DIM + kc * 32;

    float4 v4[8];
#pragma unroll
    for (int u2 = 0; u2 < 8; ++u2) v4[u2] = ((const float4*)src)[u2];

    float nsum = 0.f;
    size_t base = (size_t)kc * (N_E * 32) + (size_t)k * 32;
#pragma unroll
    for (int u = 0; u < 4; ++u) {
      float v[8] = {v4[u * 2].x, v4[u * 2].y, v4[u * 2].z, v4[u * 2].w,
                    v4[u * 2 + 1].x, v4[u * 2 + 1].y, v4[u * 2 + 1].z, v4[u * 2 + 1].w};
      f16x8 hh, ll;
#pragma unroll
      for (int j = 0; j < 8; ++j) {
        nsum = nsum + v[j] * v[j];
        float s = v[j] * ESCALE;
        _Float16 hi = (_Float16)s;
        hh[j] = hi;
        ll[j] = (_Float16)(s - (float)hi);
      }
      *(f16x8*)&Bh[base + (size_t)(u ^ perm) * 8] = hh;
      *(f16x8*)&Bl[base + (size_t)(u ^ perm) * 8] = ll;
    }
    sNP[kc][rl] = nsum;
    __syncthreads();
    if (t < 32) {
      float s = 0.f;
#pragma unroll
      for (int kc2 = 0; kc2 < 8; ++kc2) s += sNP[kc2][t];
      eNorm[be * 32 + t] = s;
    }
  }
}

// ---------- main: 3-pass fp16-limb MFMA GEMM, block 128x128, wave 64x64 ----------
// R12 config (proven best): launch_bounds(256,4) -> occupancy 42.8%, MfmaUtil 42.6%,
// VGPR 64, 0 conflicts, 226.4 us. (3 waves: 245.6 us; 5 waves: VGPR-spill cliff, 498 us.)
__global__ __launch_bounds__(256, 4) void k_scores_mfma(
    const _Float16* __restrict__ Ah, const _Float16* __restrict__ Al,
    const _Float16* __restrict__ Bh, const _Float16* __restrict__ Bl,
    const float* __restrict__ eNorm, const float* __restrict__ zNorm,
    float* __restrict__ pVal, int* __restrict__ pIdx) {
#pragma clang fp contract(off)
  __shared__ alignas(16) _Float16 As[2][128][32];  // 16 KB: limb, row, swizzled 32 f16
  __shared__ alignas(16) _Float16 Bs[2][128][32];  // 16 KB

  const int mt = blockIdx.x, nt = blockIdx.y;
  const int m0 = mt * 128, n0 = nt * 128;

  const int t = threadIdx.x;
  const int lane = t & 63, w = t >> 6;
  const int tx = lane & 15, quad = lane >> 4;
  const int wm = (w >> 1) * 64, wn = (w & 1) * 64;
  const int swz = (quad ^ ((tx >> 1) & 3)) * 8;    // physical f16 offset of logical block

  const _Float16* gseg;
  size_t plane;
  _Float16* lseg;
  if (w == 0)      { gseg = Ah + (size_t)m0 * 32; plane = (size_t)N_ROWS * 32; lseg = &As[0][0][0]; }
  else if (w == 1) { gseg = Al + (size_t)m0 * 32; plane = (size_t)N_ROWS * 32; lseg = &As[1][0][0]; }
  else if (w == 2) { gseg = Bh + (size_t)n0 * 32; plane = (size_t)N_E * 32;    lseg = &Bs[0][0][0]; }
  else             { gseg = Bl + (size_t)n0 * 32; plane = (size_t)N_E * 32;    lseg = &Bs[1][0][0]; }

  f32x4 acc[4][4];
#pragma unroll
  for (int i = 0; i < 4; ++i)
#pragma unroll
    for (int j = 0; j < 4; ++j) acc[i][j] = (f32x4){0.f, 0.f, 0.f, 0.f};

  for (int kc = 0; kc < 8; ++kc) {
    __syncthreads();                       // previous iteration's frag reads done
    const _Float16* g = gseg + (size_t)kc * plane + lane * 8;
#pragma unroll
    for (int c = 0; c < 8; ++c)
      gld_lds16(lseg + c * 512, g + c * 512);   // 8 x 1KB async copies per wave
    __syncthreads();                       // vmcnt(0) drained before barrier -> data visible

    f16x8 bh[4], bl[4];
#pragma unroll
    for (int j = 0; j < 4; ++j) {
      bh[j] = *(const f16x8*)&Bs[0][wn + j * 16 + tx][swz];
      bl[j] = *(const f16x8*)&Bs[1][wn + j * 16 + tx][swz];
    }
#pragma unroll
    for (int i = 0; i < 4; ++i) {
      f16x8 ah = *(const f16x8*)&As[0][wm + i * 16 + tx][swz];
      f16x8 al = *(const f16x8*)&As[1][wm + i * 16 + tx][swz];
#pragma unroll
      for (int j = 0; j < 4; ++j) {
        acc[i][j] = __builtin_amdgcn_mfma_f32_16x16x32_f16(ah, bh[j], acc[i][j], 0, 0, 0);
        acc[i][j] = __builtin_amdgcn_mfma_f32_16x16x32_f16(ah, bl[j], acc[i][j], 0, 0, 0);
        acc[i][j] = __builtin_amdgcn_mfma_f32_16x16x32_f16(al, bh[j], acc[i][j], 0, 0, 0);
      }
    }
  }

  // ---- epilogue: score + argmin (first-index tie-break) ----
  __syncthreads();
  float* sF  = (float*)&As[0][0][0];
  float* zNl = sF;                 // [128]
  float* eNl = sF + 128;           // [128]
  float* sV  = sF + 256;           // [2][128]
  int*   sI  = (int*)(sF + 512);   // [2][128]
  if (t < 128) zNl[t] = zNorm[m0 + t];
  else         eNl[t - 128] = eNorm[n0 + t - 128];
  __syncthreads();

#pragma unroll
  for (int i = 0; i < 4; ++i) {
#pragma unroll
    for (int r = 0; r < 4; ++r) {
      const int rloc = wm + i * 16 + quad * 4 + r;
      const float zn = zNl[rloc];
      float bv = 3.4e38f;
      int bc = 0x7fffffff;
#pragma unroll
      for (int j = 0; j < 4; ++j) {
        const int col = wn + j * 16 + tx;
        float s = (zn + eNl[col]) - acc[i][j][r] * UNSCALE;
        if (s < bv) { bv = s; bc = n0 + col; }   // j ascending: strict < keeps lowest col
      }
#pragma unroll
      for (int off = 1; off < 16; off <<= 1) {
        float ov = __shfl_xor(bv, off, 64);
        int oc = __shfl_xor(bc, off, 64);
        if (ov < bv || (ov == bv && oc < bc)) { bv = ov; bc = oc; }
      }
      if (tx == 0) { sV[(w & 1) * 128 + rloc] = bv; sI[(w & 1) * 128 + rloc] = bc; }
    }
  }
  __syncthreads();
  if (t < 128) {
    float v0 = sV[t], v1 = sV[128 + t];
    int i0 = sI[t], i1 = sI[128 + t];
    int take1 = (v1 < v0) || (v1 == v0 && i1 < i0);
    pVal[(size_t)nt * N_ROWS + m0 + t] = take1 ? v1 : v0;
    pIdx[(size_t)nt * N_ROWS + m0 + t] = take1 ? i1 : i0;
  }
}

// ---------- fused post (verbatim R11/R12, passed) ----------
__global__ __launch_bounds__(256) void k_post(const float* __restrict__ pVal,
                                              const int* __restrict__ pIdx,
                                              const float* __restrict__ z,
                                              const float* __restrict__ E,
                                              float* __restrict__ out,
                                              float* __restrict__ out_loss,
                                              float* __restrict__ out_idx) {
  __shared__ float sV[8][32];
  __shared__ int   sI[8][32];
  __shared__ int   fI[32];
  const int t = threadIdx.x;
  const int r = t & 31, s = t >> 5;
  const int n0 = blockIdx.x * 32;
  const int n = n0 + r;

  float mv = 3.4e38f;
  int mi = 0x7fffffff;
#pragma unroll
  for (int i = 0; i < 16; ++i) {
    int s2 = s * 16 + i;
    float v = pVal[(size_t)s2 * N_ROWS + n];
    int id = pIdx[(size_t)s2 * N_ROWS + n];
    if (v < mv || (v == mv && id < mi)) { mv = v; mi = id; }
  }
  sV[s][r] = mv;
  sI[s][r] = mi;
  __syncthreads();
  if (t < 32) {
    float bv = sV[0][t];
    int bc = sI[0][t];
#pragma unroll
    for (int s3 = 1; s3 < 8; ++s3) {
      float v = sV[s3][t];
      int id = sI[s3][t];
      if (v < bv || (v == bv && id < bc)) { bv = v; bc = id; }
    }
    fI[t] = bc;
    out_idx[n0 + t] = (float)bc;
  }
  __syncthreads();

  const int idx = fI[r];
  const int b = n >> 10, hw = n & 1023;
  const float4* erow4 = (const float4*)(E + (size_t)idx * E_DIM + s * 32);
  const float* zrow = z + ((size_t)b * E_DIM + s * 32) * HW + hw;
  float* orow = out + ((size_t)b * E_DIM + s * 32) * HW + hw;
  float acc = 0.f;
#pragma unroll
  for (int c4 = 0; c4 < 8; ++c4) {
    float4 e4 = erow4[c4];
    float ev[4] = {e4.x, e4.y, e4.z, e4.w};
#pragma unroll
    for (int j2 = 0; j2 < 4; ++j2) {
      int c = c4 * 4 + j2;
      float zv = zrow[(size_t)c * HW];
      orow[(size_t)c * HW] = ev[j2];
      float d = ev[j2] - zv;
      acc = fmaf(d, d, acc);
    }
  }
  for (int off = 32; off > 0; off >>= 1) acc += __shfl_down(acc, off, 64);
  __shared__ float wsum[4];
  if ((t & 63) == 0) wsum[t >> 6] = acc;
  __syncthreads();
  if (t == 0)
    atomicAdd(out_loss, ((wsum[0] + wsum[1]) + (wsum[2] + wsum[3])) * (1.25f / 2097152.f));
}

extern "C" void kernel_launch(void* const* d_in, const int* in_sizes, int n_in,
                              void* d_out, int out_size, void* d_ws, size_t ws_size,
                              hipStream_t stream) {
  const float* z = (const float*)d_in[0];
  const float* E = (const float*)d_in[1];
  float* out = (float*)d_out;
  float* out_loss = out + 2097152;  // after z_q (8*256*32*32)
  float* out_idx = out + 2097153;

  // workspace (~32 MB): Ah|Al f16[8][8192][32], Bh|Bl f16[8][16384][32],
  //                     eNorm, zNorm, pVal[128][8192], pIdx[128][8192]
  _Float16* Ah = (_Float16*)d_ws;
  _Float16* Al = Ah + (size_t)N_ROWS * E_DIM;
  _Float16* Bh = Al + (size_t)N_ROWS * E_DIM;
  _Float16* Bl = Bh + (size_t)N_E * E_DIM;
  float* eNorm = (float*)(Bl + (size_t)N_E * E_DIM);
  float* zNorm = eNorm + N_E;
  float* pVal = zNorm + N_ROWS;
  int* pIdx = (int*)(pVal + (size_t)NPART * N_ROWS);

  k_prep<<<ZB_Z + EB_E, 256, 0, stream>>>(
      z, E, Ah, Al, Bh, Bl, eNorm, zNorm, out_loss);
  k_scores_mfma<<<dim3(N_ROWS / 128, N_E / 128), 256, 0, stream>>>(
      Ah, Al, Bh, Bl, eNorm, zNorm, pVal, pIdx);
  k_post<<<N_ROWS / 32, 256, 0, stream>>>(pVal, pIdx, z, E, out, out_loss, out_idx);
}